// Round 6
// baseline (417.585 us; speedup 1.0000x reference)
//
#include <hip/hip_runtime.h>

#define NN 4096
#define DD 256
#define EE 131072

typedef __attribute__((ext_vector_type(8))) short s16x8;
typedef __attribute__((ext_vector_type(4))) float f32x4;

__device__ __forceinline__ unsigned short f2bf(float f) {
  unsigned u = __builtin_bit_cast(unsigned, f);
  u += 0x7FFFu + ((u >> 16) & 1u);
  return (unsigned short)(u >> 16);
}

__device__ __forceinline__ ushort4 cvt4(f32x4 v) {
  ushort4 r;
  r.x = f2bf(v[0]); r.y = f2bf(v[1]); r.z = f2bf(v[2]); r.w = f2bf(v[3]);
  return r;
}

// round-half-up fp32->bf16 pair pack: 2 adds + 1 v_perm
__device__ __forceinline__ unsigned cvt2_rhu(float a, float b) {
  unsigned ua = __builtin_bit_cast(unsigned, a) + 0x8000u;
  unsigned ub = __builtin_bit_cast(unsigned, b) + 0x8000u;
  return __builtin_amdgcn_perm(ub, ua, 0x07060302u);
}

__device__ __forceinline__ uint4 pack8(f32x4 a, f32x4 b) {
  uint4 r;
  r.x = cvt2_rhu(a[0], a[1]); r.y = cvt2_rhu(a[2], a[3]);
  r.z = cvt2_rhu(b[0], b[1]); r.w = cvt2_rhu(b[2], b[3]);
  return r;
}

__device__ __forceinline__ s16x8 pack8f(f32x4 a, f32x4 b) {
  uint4 p = pack8(a, b);
  return __builtin_bit_cast(s16x8, p);
}

// B fragment layout (consumed by mfma_16x16x32_bf16 B-operand):
//   element (n, k) of a 256-col operand lives at ushort index
//   (tile*128 + kc)*512 + (quad*16 + (n&15))*8 + (k&7)
//   tile = n>>4, kc = k>>5, quad = (k>>3)&3.  One wave chunk-load = 1KB coalesced.

// ---------------------------------------------------------------------------
// K1: count in-degrees + write both W matrices in B-fragment layout (bf16)
// ---------------------------------------------------------------------------
__global__ void k_prep(const int* __restrict__ ei, int* __restrict__ deg,
                       const float* __restrict__ Wh, const float* __restrict__ Wc,
                       unsigned short* __restrict__ WFh, unsigned short* __restrict__ WFc) {
  int t = blockIdx.x * 256 + threadIdx.x;
  if (t < EE) {
    atomicAdd(&deg[ei[EE + t]], 1);
  } else {
    int idx = t - EE;                 // 0..131071
    int which = idx >> 16;            // 0: W_high, 1: W_conv
    int r = idx & 65535;
    int n = r & 255, k = r >> 8;      // consecutive threads -> consecutive n (coalesced read)
    const float* W = which ? Wc : Wh;
    unsigned short* WF = which ? WFc : WFh;
    long fidx = ((long)((n >> 4) * 8 + (k >> 5))) * 512 +
                (((k >> 3) & 3) * 16 + (n & 15)) * 8 + (k & 7);
    WF[fidx] = f2bf(W[k * 256 + n]);  // fragment(n,k) = W[k][n]
  }
}

// ---------------------------------------------------------------------------
// K2: exclusive scan of deg -> row_start[4097]; dis = rsqrt(deg+1)
// ---------------------------------------------------------------------------
__global__ void k_scan(const int* __restrict__ deg, int* __restrict__ row_start,
                       float* __restrict__ dis) {
  __shared__ int part[1024];
  int t = threadIdx.x;
  int d0 = deg[4 * t + 0], d1 = deg[4 * t + 1], d2 = deg[4 * t + 2], d3 = deg[4 * t + 3];
  int s = d0 + d1 + d2 + d3;
  part[t] = s;
  __syncthreads();
  for (int off = 1; off < 1024; off <<= 1) {
    int add = (t >= off) ? part[t - off] : 0;
    __syncthreads();
    part[t] += add;
    __syncthreads();
  }
  int base = part[t] - s;
  row_start[4 * t + 0] = base;
  row_start[4 * t + 1] = base + d0;
  row_start[4 * t + 2] = base + d0 + d1;
  row_start[4 * t + 3] = base + d0 + d1 + d2;
  if (t == 1023) row_start[4096] = part[t];
  dis[4 * t + 0] = rsqrtf((float)d0 + 1.0f);
  dis[4 * t + 1] = rsqrtf((float)d1 + 1.0f);
  dis[4 * t + 2] = rsqrtf((float)d2 + 1.0f);
  dis[4 * t + 3] = rsqrtf((float)d3 + 1.0f);
}

// ---------------------------------------------------------------------------
// K3: scatter edges into CSR buckets
// ---------------------------------------------------------------------------
__global__ void k_scatter(const int* __restrict__ ei, const int* __restrict__ row_start,
                          int* __restrict__ cursor, int* __restrict__ csr) {
  int e = blockIdx.x * 256 + threadIdx.x;
  if (e < EE) {
    int s = ei[e];
    int d = ei[EE + e];
    int p = atomicAdd(&cursor[d], 1);
    csr[row_start[d] + p] = s;
  }
}

// ---------------------------------------------------------------------------
// K4: RF = frag(relu(x @ W_high))  and  XWs[m][n] = dis[m] * (x @ W_conv)[m][n]
//     grid 256 (16-row M-tiles), block 512. waves 0-3: high, 4-7: conv.
// ---------------------------------------------------------------------------
__global__ __launch_bounds__(512) void k_xw(const float* __restrict__ x,
                                            const unsigned short* __restrict__ WFh,
                                            const unsigned short* __restrict__ WFc,
                                            unsigned short* __restrict__ RF,
                                            float* __restrict__ XWs,
                                            const float* __restrict__ dis) {
  __shared__ alignas(16) unsigned short Abuf[16][264];
  const int tid = threadIdx.x;
  const int w = tid >> 6, lane = tid & 63;
  const int quad = lane >> 4, l16 = lane & 15, quad8 = quad * 8;
  const int m0 = blockIdx.x * 16;

  {
    int srow = tid >> 5, scolf = (tid & 31) * 8;
    const float* ap = x + (long)(m0 + srow) * DD + scolf;
    f32x4 a0 = *(const f32x4*)ap;
    f32x4 a1 = *(const f32x4*)(ap + 4);
    *(uint4*)&Abuf[srow][scolf] = pack8(a0, a1);
  }
  __syncthreads();

  const bool hi = (w < 4);
  const int wo = hi ? w : (w - 4);
  const unsigned short* WF = hi ? WFh : WFc;
  const unsigned short* bp = WF + lane * 8;

  f32x4 acc[4] = {{0,0,0,0},{0,0,0,0},{0,0,0,0},{0,0,0,0}};
#pragma unroll
  for (int q = 0; q < 8; ++q) {
    s16x8 af = *(const s16x8*)&Abuf[l16][q * 32 + quad8];
#pragma unroll
    for (int s = 0; s < 4; ++s) {
      s16x8 bf = *(const s16x8*)(bp + ((long)((4 * wo + s) * 8 + q)) * 512);
      acc[s] = __builtin_amdgcn_mfma_f32_16x16x32_bf16(af, bf, acc[s], 0, 0, 0);
    }
  }

  if (hi) {
    const int kc = m0 >> 5;
    const int qp = ((m0 >> 4) & 1) * 2 + (quad >> 1);
    const int j0 = (quad & 1) * 4;
#pragma unroll
    for (int s = 0; s < 4; ++s) {
      int t = 4 * wo + s;
      f32x4 v = acc[s];
      f32x4 z;
      z[0] = v[0] > 0.f ? v[0] : 0.f;
      z[1] = v[1] > 0.f ? v[1] : 0.f;
      z[2] = v[2] > 0.f ? v[2] : 0.f;
      z[3] = v[3] > 0.f ? v[3] : 0.f;
      long idx = ((long)(t * 128 + kc)) * 512 + (qp * 16 + l16) * 8 + j0;
      *(ushort4*)(RF + idx) = cvt4(z);
    }
  } else {
    float dm[4];
#pragma unroll
    for (int r = 0; r < 4; ++r) dm[r] = dis[m0 + quad * 4 + r];
#pragma unroll
    for (int s = 0; s < 4; ++s) {
      int col = 64 * wo + 16 * s + l16;
#pragma unroll
      for (int r = 0; r < 4; ++r)
        XWs[(long)(m0 + quad * 4 + r) * DD + col] = dm[r] * acc[s][r];
    }
  }
}

// ---------------------------------------------------------------------------
// K5: GCN aggregation, dis pre-multiplied into XWs; unroll-by-4 gathers
// ---------------------------------------------------------------------------
__global__ void k_agg(const float* __restrict__ XWs, const int* __restrict__ row_start,
                      const int* __restrict__ csr, const float* __restrict__ dis,
                      float* __restrict__ Hl) {
  const int i = blockIdx.x;
  const int t = threadIdx.x;
  const int b0 = row_start[i], b1 = row_start[i + 1];
  float acc = XWs[(long)i * DD + t];   // self loop
  int j = b0;
  for (; j + 4 <= b1; j += 4) {
    int s0 = csr[j], s1 = csr[j + 1], s2 = csr[j + 2], s3 = csr[j + 3];
    float v0 = XWs[(long)s0 * DD + t];
    float v1 = XWs[(long)s1 * DD + t];
    float v2 = XWs[(long)s2 * DD + t];
    float v3 = XWs[(long)s3 * DD + t];
    acc += (v0 + v1) + (v2 + v3);
  }
  for (; j < b1; ++j) acc += XWs[(long)csr[j] * DD + t];
  Hl[(long)i * DD + t] = dis[i] * acc;
}

// ---------------------------------------------------------------------------
// K6: C[4096 x 256] = A[4096 x 4096](fp32) @ B, B in fragment layout (bf16).
//     BARRIER-FREE per-wave streaming, STRAIGHT-LINE K-loop (no branches).
//     Evidence R2/R5: VGPR=80 (pipeline collapsed) with `if (g+2<32) LDG`
//     guarded prefetch -- conditional loads live in a guarded BB, the
//     waitcnt pass can't count across the merge, falls back to ~vmcnt(0)
//     per consume, and live ranges collapse.  Here the prefetch group index
//     is CLAMPED with a uniform ternary (s_cselect, single basic block);
//     every iteration issues exactly one 16-load group per half, so the
//     dataflow emits counted vmcnt(16): one full group always in flight,
//     zero barriers, waves self-stagger (continuous HBM demand).
//     Geometry (R2, correctness-verified): grid 256 = 128 m-blocks (32 rows)
//     x 2 n-halves; pair (b, b+128) same XCD.  8 waves: msub = w&1 (16-row
//     half, L1-shared A across the 4 nsub waves), nsub = w>>1 (n-tiles
//     t0 = nhalf*8 + nsub*2, t0+1).  A read as 4x32B/row fragments (128B
//     contiguous per row per chunk), in-reg fp32->bf16 pack, B from L2.
//     EPI 0: write C in fragment layout (next mm's B).  EPI 3: fused final.
// ---------------------------------------------------------------------------
template <int EPI>
__global__ __launch_bounds__(512) void k_mm2(const float* __restrict__ A,
                                             const unsigned short* __restrict__ BF,
                                             unsigned short* __restrict__ CF,
                                             float* __restrict__ outF,
                                             const float* __restrict__ Hl,
                                             const float* __restrict__ bconv,
                                             const float* __restrict__ aLp,
                                             const float* __restrict__ aHp) {
  const int tid = threadIdx.x;
  const int w = tid >> 6, lane = tid & 63;
  const int quad = lane >> 4, l16 = lane & 15;
  const int mblk = blockIdx.x & 127, nhalf = blockIdx.x >> 7;
  const int msub = w & 1, nsub = w >> 1;
  const int mrow = mblk * 32 + msub * 16 + l16;    // A row this lane reads
  const int t0 = nhalf * 8 + nsub * 2;             // first n-tile of this wave

  const float* ap = A + (long)mrow * NN + quad * 8;
  const unsigned short* bp0 = BF + ((long)t0 * 128) * 512 + lane * 8;
  const unsigned short* bp1 = bp0 + 128l * 512;

  // X/Y double-buffered register pipeline; each group = 4 k-chunks of 32
  // (128 k).  32 groups cover K=4096.
  f32x4 xa0[4], xa1[4]; s16x8 xb0[4], xb1[4];
  f32x4 ya0[4], ya1[4]; s16x8 yb0[4], yb1[4];
  f32x4 acc0 = {0, 0, 0, 0}, acc1 = {0, 0, 0, 0};

// load group gi (k-floats [gi*128, gi*128+128)) into a register set
#define LDGF(a0v, a1v, b0v, b1v, gi)                             \
  {                                                              \
    const float* ap_ = ap + (long)(gi) * 128;                    \
    const unsigned short* b0_ = bp0 + (long)(gi) * 2048;         \
    const unsigned short* b1_ = bp1 + (long)(gi) * 2048;         \
    _Pragma("unroll") for (int c = 0; c < 4; ++c) {              \
      a0v[c] = *(const f32x4*)(ap_ + c * 32);                    \
      a1v[c] = *(const f32x4*)(ap_ + c * 32 + 4);                \
      b0v[c] = *(const s16x8*)(b0_ + c * 512);                   \
      b1v[c] = *(const s16x8*)(b1_ + c * 512);                   \
    }                                                            \
  }

#define CMP(a0v, a1v, b0v, b1v)                                              \
  {                                                                          \
    _Pragma("unroll") for (int c = 0; c < 4; ++c) {                          \
      s16x8 af = pack8f(a0v[c], a1v[c]);                                     \
      acc0 = __builtin_amdgcn_mfma_f32_16x16x32_bf16(af, b0v[c], acc0, 0, 0, 0); \
      acc1 = __builtin_amdgcn_mfma_f32_16x16x32_bf16(af, b1v[c], acc1, 0, 0, 0); \
    }                                                                        \
  }

  LDGF(xa0, xa1, xb0, xb1, 0);   // group 0
  __builtin_amdgcn_sched_barrier(0);
  LDGF(ya0, ya1, yb0, yb1, 1);   // group 1
  __builtin_amdgcn_sched_barrier(0);

#pragma unroll 1
  for (int g = 0; g < 16; ++g) {
    // clamped prefetch group indices: uniform select, NO branch.  Last
    // iteration harmlessly re-reads groups 0/1 (valid memory, discarded).
    const int gx = (g < 15) ? (2 * g + 2) : 0;
    const int gy = (g < 15) ? (2 * g + 3) : 1;
    CMP(xa0, xa1, xb0, xb1);            // consume group 2g
    LDGF(xa0, xa1, xb0, xb1, gx);       // prefetch
    __builtin_amdgcn_sched_barrier(0);
    CMP(ya0, ya1, yb0, yb1);            // consume group 2g+1
    LDGF(ya0, ya1, yb0, yb1, gy);       // prefetch
    __builtin_amdgcn_sched_barrier(0);
  }
#undef LDGF
#undef CMP

  if constexpr (EPI == 0) {
    // fragment(n,k): n = t*16 + l16, k = mblk*32 + msub*16 + quad*4 + r
    //   kc = mblk ; (k>>3)&3 = msub*2 + (quad>>1) ; k&7 = (quad&1)*4 + r
    const int qp = msub * 2 + (quad >> 1);
    const int j0 = (quad & 1) * 4;
    long i0 = ((long)(t0 * 128 + mblk)) * 512 + (qp * 16 + l16) * 8 + j0;
    long i1 = ((long)((t0 + 1) * 128 + mblk)) * 512 + (qp * 16 + l16) * 8 + j0;
    *(ushort4*)(CF + i0) = cvt4(acc0);
    *(ushort4*)(CF + i1) = cvt4(acc1);
  } else {
    const float aLv = aLp[0], aHv = aHp[0];
    const int mr = mblk * 32 + msub * 16 + quad * 4;
    const int c0 = t0 * 16 + l16;
    const int c1 = c0 + 16;
#pragma unroll
    for (int r = 0; r < 4; ++r) {
      int row = mr + r;
      outF[(long)row * DD + c0] =
          aHv * acc0[r] + aLv * (Hl[(long)row * DD + c0] + bconv[c0]);
      outF[(long)row * DD + c1] =
          aHv * acc1[r] + aLv * (Hl[(long)row * DD + c1] + bconv[c1]);
    }
  }
}

// ---------------------------------------------------------------------------
// launcher
// ---------------------------------------------------------------------------
extern "C" void kernel_launch(void* const* d_in, const int* in_sizes, int n_in,
                              void* d_out, int out_size, void* d_ws, size_t ws_size,
                              hipStream_t stream) {
  const float* x     = (const float*)d_in[0];
  const int*   ei    = (const int*)d_in[1];
  const float* lap   = (const float*)d_in[2];
  const float* dinv  = (const float*)d_in[3];
  const float* Wh    = (const float*)d_in[4];
  const float* Wc    = (const float*)d_in[5];
  const float* bconv = (const float*)d_in[6];
  const float* aL    = (const float*)d_in[7];
  const float* aH    = (const float*)d_in[8];
  float* out = (float*)d_out;
  char* ws = (char*)d_ws;

  int* deg        = (int*)(ws);                          // 16 KB
  int* cursor     = (int*)(ws + (16 << 10));             // 16 KB
  int* row_start  = (int*)(ws + (32 << 10));             // 16.4 KB
  int* csr        = (int*)(ws + (64 << 10));             // 512 KB
  float* dis      = (float*)(ws + (576 << 10));          // 16 KB
  unsigned short* WFh = (unsigned short*)(ws + (1l << 20));               // 128 KB
  unsigned short* WFc = (unsigned short*)(ws + (1l << 20) + (128 << 10)); // 128 KB
  unsigned short* RF  = (unsigned short*)(ws + (2l << 20));  // 2 MB fragment layout
  unsigned short* T1F = (unsigned short*)(ws + (4l << 20));  // 2 MB
  unsigned short* T2F = (unsigned short*)(ws + (6l << 20));  // 2 MB
  float* XWs = (float*)(ws + (8l << 20));                    // 4 MB
  float* Hl  = (float*)(ws + (12l << 20));                   // 4 MB

  hipMemsetAsync(ws, 0, 32 << 10, stream);   // deg + cursor

  k_prep<<<1024, 256, 0, stream>>>(ei, deg, Wh, Wc, WFh, WFc);
  k_scan<<<1, 1024, 0, stream>>>(deg, row_start, dis);
  k_scatter<<<512, 256, 0, stream>>>(ei, row_start, cursor, csr);
  k_xw<<<256, 512, 0, stream>>>(x, WFh, WFc, RF, XWs, dis);
  k_agg<<<4096, 256, 0, stream>>>(XWs, row_start, csr, dis, Hl);

  k_mm2<0><<<256, 512, 0, stream>>>(dinv, RF, T1F, nullptr, nullptr, nullptr, nullptr, nullptr);
  k_mm2<0><<<256, 512, 0, stream>>>(lap, T1F, T2F, nullptr, nullptr, nullptr, nullptr, nullptr);
  k_mm2<3><<<256, 512, 0, stream>>>(dinv, T2F, nullptr, out, Hl, bconv, aL, aH);
}

// Round 7
// 339.572 us; speedup vs baseline: 1.2297x; 1.2297x over previous
//
#include <hip/hip_runtime.h>

#define NN 4096
#define DD 256
#define EE 131072

typedef __attribute__((ext_vector_type(8))) short s16x8;
typedef __attribute__((ext_vector_type(4))) float f32x4;

__device__ __forceinline__ unsigned short f2bf(float f) {
  unsigned u = __builtin_bit_cast(unsigned, f);
  u += 0x7FFFu + ((u >> 16) & 1u);
  return (unsigned short)(u >> 16);
}

__device__ __forceinline__ ushort4 cvt4(f32x4 v) {
  ushort4 r;
  r.x = f2bf(v[0]); r.y = f2bf(v[1]); r.z = f2bf(v[2]); r.w = f2bf(v[3]);
  return r;
}

// round-half-up fp32->bf16 pair pack: 2 adds + 1 v_perm
__device__ __forceinline__ unsigned cvt2_rhu(float a, float b) {
  unsigned ua = __builtin_bit_cast(unsigned, a) + 0x8000u;
  unsigned ub = __builtin_bit_cast(unsigned, b) + 0x8000u;
  return __builtin_amdgcn_perm(ub, ua, 0x07060302u);
}

__device__ __forceinline__ uint4 pack8(f32x4 a, f32x4 b) {
  uint4 r;
  r.x = cvt2_rhu(a[0], a[1]); r.y = cvt2_rhu(a[2], a[3]);
  r.z = cvt2_rhu(b[0], b[1]); r.w = cvt2_rhu(b[2], b[3]);
  return r;
}

__device__ __forceinline__ s16x8 pack8f(f32x4 a, f32x4 b) {
  uint4 p = pack8(a, b);
  return __builtin_bit_cast(s16x8, p);
}

// async global->LDS, 16B per lane; LDS dest must be wave-uniform base + lane*16
__device__ __forceinline__ void gl2lds(const float* g, float* l) {
  __builtin_amdgcn_global_load_lds(
      (const __attribute__((address_space(1))) unsigned*)g,
      (__attribute__((address_space(3))) unsigned*)l, 16, 0, 0);
}

// B fragment layout (consumed by mfma_16x16x32_bf16 B-operand):
//   element (n, k) of a 256-col operand lives at ushort index
//   (tile*128 + kc)*512 + (quad*16 + (n&15))*8 + (k&7)
//   tile = n>>4, kc = k>>5, quad = (k>>3)&3.  One chunk = 1KB contiguous.

// ---------------------------------------------------------------------------
// K1: count in-degrees + write both W matrices in B-fragment layout (bf16)
// ---------------------------------------------------------------------------
__global__ void k_prep(const int* __restrict__ ei, int* __restrict__ deg,
                       const float* __restrict__ Wh, const float* __restrict__ Wc,
                       unsigned short* __restrict__ WFh, unsigned short* __restrict__ WFc) {
  int t = blockIdx.x * 256 + threadIdx.x;
  if (t < EE) {
    atomicAdd(&deg[ei[EE + t]], 1);
  } else {
    int idx = t - EE;                 // 0..131071
    int which = idx >> 16;            // 0: W_high, 1: W_conv
    int r = idx & 65535;
    int n = r & 255, k = r >> 8;      // consecutive threads -> consecutive n (coalesced read)
    const float* W = which ? Wc : Wh;
    unsigned short* WF = which ? WFc : WFh;
    long fidx = ((long)((n >> 4) * 8 + (k >> 5))) * 512 +
                (((k >> 3) & 3) * 16 + (n & 15)) * 8 + (k & 7);
    WF[fidx] = f2bf(W[k * 256 + n]);  // fragment(n,k) = W[k][n]
  }
}

// ---------------------------------------------------------------------------
// K2: exclusive scan of deg -> row_start[4097]; dis = rsqrt(deg+1)
// ---------------------------------------------------------------------------
__global__ void k_scan(const int* __restrict__ deg, int* __restrict__ row_start,
                       float* __restrict__ dis) {
  __shared__ int part[1024];
  int t = threadIdx.x;
  int d0 = deg[4 * t + 0], d1 = deg[4 * t + 1], d2 = deg[4 * t + 2], d3 = deg[4 * t + 3];
  int s = d0 + d1 + d2 + d3;
  part[t] = s;
  __syncthreads();
  for (int off = 1; off < 1024; off <<= 1) {
    int add = (t >= off) ? part[t - off] : 0;
    __syncthreads();
    part[t] += add;
    __syncthreads();
  }
  int base = part[t] - s;
  row_start[4 * t + 0] = base;
  row_start[4 * t + 1] = base + d0;
  row_start[4 * t + 2] = base + d0 + d1;
  row_start[4 * t + 3] = base + d0 + d1 + d2;
  if (t == 1023) row_start[4096] = part[t];
  dis[4 * t + 0] = rsqrtf((float)d0 + 1.0f);
  dis[4 * t + 1] = rsqrtf((float)d1 + 1.0f);
  dis[4 * t + 2] = rsqrtf((float)d2 + 1.0f);
  dis[4 * t + 3] = rsqrtf((float)d3 + 1.0f);
}

// ---------------------------------------------------------------------------
// K3: scatter edges into CSR buckets
// ---------------------------------------------------------------------------
__global__ void k_scatter(const int* __restrict__ ei, const int* __restrict__ row_start,
                          int* __restrict__ cursor, int* __restrict__ csr) {
  int e = blockIdx.x * 256 + threadIdx.x;
  if (e < EE) {
    int s = ei[e];
    int d = ei[EE + e];
    int p = atomicAdd(&cursor[d], 1);
    csr[row_start[d] + p] = s;
  }
}

// ---------------------------------------------------------------------------
// K4: RF = frag(relu(x @ W_high))  and  XWs[m][n] = dis[m] * (x @ W_conv)[m][n]
//     grid 256 (16-row M-tiles), block 512. waves 0-3: high, 4-7: conv.
// ---------------------------------------------------------------------------
__global__ __launch_bounds__(512) void k_xw(const float* __restrict__ x,
                                            const unsigned short* __restrict__ WFh,
                                            const unsigned short* __restrict__ WFc,
                                            unsigned short* __restrict__ RF,
                                            float* __restrict__ XWs,
                                            const float* __restrict__ dis) {
  __shared__ alignas(16) unsigned short Abuf[16][264];
  const int tid = threadIdx.x;
  const int w = tid >> 6, lane = tid & 63;
  const int quad = lane >> 4, l16 = lane & 15, quad8 = quad * 8;
  const int m0 = blockIdx.x * 16;

  {
    int srow = tid >> 5, scolf = (tid & 31) * 8;
    const float* ap = x + (long)(m0 + srow) * DD + scolf;
    f32x4 a0 = *(const f32x4*)ap;
    f32x4 a1 = *(const f32x4*)(ap + 4);
    *(uint4*)&Abuf[srow][scolf] = pack8(a0, a1);
  }
  __syncthreads();

  const bool hi = (w < 4);
  const int wo = hi ? w : (w - 4);
  const unsigned short* WF = hi ? WFh : WFc;
  const unsigned short* bp = WF + lane * 8;

  f32x4 acc[4] = {{0,0,0,0},{0,0,0,0},{0,0,0,0},{0,0,0,0}};
#pragma unroll
  for (int q = 0; q < 8; ++q) {
    s16x8 af = *(const s16x8*)&Abuf[l16][q * 32 + quad8];
#pragma unroll
    for (int s = 0; s < 4; ++s) {
      s16x8 bf = *(const s16x8*)(bp + ((long)((4 * wo + s) * 8 + q)) * 512);
      acc[s] = __builtin_amdgcn_mfma_f32_16x16x32_bf16(af, bf, acc[s], 0, 0, 0);
    }
  }

  if (hi) {
    const int kc = m0 >> 5;
    const int qp = ((m0 >> 4) & 1) * 2 + (quad >> 1);
    const int j0 = (quad & 1) * 4;
#pragma unroll
    for (int s = 0; s < 4; ++s) {
      int t = 4 * wo + s;
      f32x4 v = acc[s];
      f32x4 z;
      z[0] = v[0] > 0.f ? v[0] : 0.f;
      z[1] = v[1] > 0.f ? v[1] : 0.f;
      z[2] = v[2] > 0.f ? v[2] : 0.f;
      z[3] = v[3] > 0.f ? v[3] : 0.f;
      long idx = ((long)(t * 128 + kc)) * 512 + (qp * 16 + l16) * 8 + j0;
      *(ushort4*)(RF + idx) = cvt4(z);
    }
  } else {
    float dm[4];
#pragma unroll
    for (int r = 0; r < 4; ++r) dm[r] = dis[m0 + quad * 4 + r];
#pragma unroll
    for (int s = 0; s < 4; ++s) {
      int col = 64 * wo + 16 * s + l16;
#pragma unroll
      for (int r = 0; r < 4; ++r)
        XWs[(long)(m0 + quad * 4 + r) * DD + col] = dm[r] * acc[s][r];
    }
  }
}

// ---------------------------------------------------------------------------
// K5: GCN aggregation, dis pre-multiplied into XWs; unroll-by-4 gathers
// ---------------------------------------------------------------------------
__global__ void k_agg(const float* __restrict__ XWs, const int* __restrict__ row_start,
                      const int* __restrict__ csr, const float* __restrict__ dis,
                      float* __restrict__ Hl) {
  const int i = blockIdx.x;
  const int t = threadIdx.x;
  const int b0 = row_start[i], b1 = row_start[i + 1];
  float acc = XWs[(long)i * DD + t];   // self loop
  int j = b0;
  for (; j + 4 <= b1; j += 4) {
    int s0 = csr[j], s1 = csr[j + 1], s2 = csr[j + 2], s3 = csr[j + 3];
    float v0 = XWs[(long)s0 * DD + t];
    float v1 = XWs[(long)s1 * DD + t];
    float v2 = XWs[(long)s2 * DD + t];
    float v3 = XWs[(long)s3 * DD + t];
    acc += (v0 + v1) + (v2 + v3);
  }
  for (; j < b1; ++j) acc += XWs[(long)csr[j] * DD + t];
  Hl[(long)i * DD + t] = dis[i] * acc;
}

// ---------------------------------------------------------------------------
// K6: m97-structure split-K GEMM.  C32 += A[4096x4096](fp32) @ B(frag bf16).
//     Tile 128x128, BK=64, 8 K-steps (K=512 per block), split-K x8 via
//     fp32 atomicAdd (device-scope, m20).  grid 512 = 32 mblk x 8 ksplit x
//     2 nhalf; pair (h=0,1) adjacent (L2/L3 dedups A).  Block 256 = 4 waves,
//     wave w owns rows [w*32, w*32+32), all 128 cols: acc 2x8 frags (64 VGPR).
//     BOTH operands staged via global_load_lds (nothing through VGPRs ->
//     nothing for hipcc to collapse; R2/R5/R6 law).  A fp32 source-granule
//     XOR-swizzled (gi ^ (row&7)) so ds_read_b128 frag reads hit all 32
//     banks; pack fp32->bf16 on the LDS-read side (pure VALU).
//     48 KB LDS single-buffer -> 3 blocks/CU: rich per-stage work
//     (~32 MFMA + 24 ds_read + 8 pack per wave) lets co-resident blocks
//     fill each other's vmcnt(0)+barrier drain (m97/m114 regime).
// ---------------------------------------------------------------------------
__global__ __launch_bounds__(256, 3) void k_mm3(const float* __restrict__ A,
                                                const unsigned short* __restrict__ BF,
                                                float* __restrict__ C32) {
  __shared__ alignas(16) float Af[128 * 64];          // 32 KB
  __shared__ alignas(16) unsigned short Bs[8192];     // 16 KB
  const int tid = threadIdx.x;
  const int bid = blockIdx.x;
  const int mblk = bid >> 4;          // 0..31
  const int ks = (bid >> 1) & 7;      // 0..7
  const int h = bid & 1;              // 0..1
  const int m0 = mblk * 128;
  const int k0 = ks * 512;

  const int w = tid >> 6, lane = tid & 63;
  const int quad = lane >> 4, l16 = lane & 15;

  // --- staging addresses -------------------------------------------------
  // A: thread t stages rows (t>>4) + 16p, granule (t&15); source granule
  //    pre-swizzled sg = (t&15) ^ (row&7)  (row&7 == (t>>4)&7, p*16 == 0 mod 8)
  const int ar = tid >> 4;
  const int sg = (tid & 15) ^ (ar & 7);
  const float* asrc = A + (long)(m0 + ar) * NN + k0 + sg * 4;
  float* adst = Af + tid * 4;
  // B: 1024 granules = 8 tiles x (2 chunks = 1024 shorts); thread t stages
  //    granules t + 256j.  Chunk window per step: kc = ks*16 + s*2.
  const unsigned short* bsrc[4];
#pragma unroll
  for (int j = 0; j < 4; ++j) {
    int gb = tid + 256 * j, ti = gb >> 7, wi = gb & 127;
    bsrc[j] = BF + ((long)(h * 8 + ti) * 128 + ks * 16) * 512 + wi * 8;
  }
  float* bdst = (float*)Bs + tid * 4;

#define STAGE(s)                                                          \
  {                                                                       \
    _Pragma("unroll") for (int p = 0; p < 8; ++p)                         \
        gl2lds(asrc + (long)p * (16 * NN) + (s) * 64, adst + p * 1024);   \
    _Pragma("unroll") for (int j = 0; j < 4; ++j)                         \
        gl2lds((const float*)(bsrc[j] + (s) * 1024), bdst + j * 1024);    \
  }

  f32x4 acc0[8], acc1[8];
#pragma unroll
  for (int i = 0; i < 8; ++i) {
    acc0[i] = (f32x4){0.f, 0.f, 0.f, 0.f};
    acc1[i] = (f32x4){0.f, 0.f, 0.f, 0.f};
  }

  const int lr0 = w * 32 + l16;
  const int xr = l16 & 7;                       // (lr0 & 7) == (lr0+16 & 7)
  const float* arb0 = Af + lr0 * 64;
  const float* arb1 = Af + (lr0 + 16) * 64;
  const unsigned short* bl = Bs + lane * 8;

  STAGE(0);
#pragma unroll 1
  for (int s = 0; s < 8; ++s) {
    __syncthreads();                            // vmcnt(0) drain: stage s landed
#pragma unroll
    for (int c = 0; c < 2; ++c) {
      const int g = c * 8 + quad * 2;
      f32x4 lo0 = *(const f32x4*)(arb0 + (g ^ xr) * 4);
      f32x4 hi0 = *(const f32x4*)(arb0 + ((g + 1) ^ xr) * 4);
      f32x4 lo1 = *(const f32x4*)(arb1 + (g ^ xr) * 4);
      f32x4 hi1 = *(const f32x4*)(arb1 + ((g + 1) ^ xr) * 4);
      s16x8 af0 = pack8f(lo0, hi0);
      s16x8 af1 = pack8f(lo1, hi1);
#pragma unroll
      for (int ni = 0; ni < 8; ++ni) {
        s16x8 bf = *(const s16x8*)(bl + (ni * 2 + c) * 512);
        acc0[ni] = __builtin_amdgcn_mfma_f32_16x16x32_bf16(af0, bf, acc0[ni], 0, 0, 0);
        acc1[ni] = __builtin_amdgcn_mfma_f32_16x16x32_bf16(af1, bf, acc1[ni], 0, 0, 0);
      }
    }
    __syncthreads();                            // all waves done reading LDS
    if (s < 7) STAGE(s + 1);
  }
#undef STAGE

  // --- epilogue: fp32 atomic accumulate (split-K reduction) --------------
  const int grow = m0 + w * 32 + quad * 4;
  const int gcol = h * 128 + l16;
#pragma unroll
  for (int ni = 0; ni < 8; ++ni)
#pragma unroll
    for (int r = 0; r < 4; ++r) {
      atomicAdd(&C32[(long)(grow + r) * DD + gcol + ni * 16], acc0[ni][r]);
      atomicAdd(&C32[(long)(grow + 16 + r) * DD + gcol + ni * 16], acc1[ni][r]);
    }
}

// ---------------------------------------------------------------------------
// K7: convert fp32 C -> bf16 B-fragment layout (input of the next k_mm3)
// ---------------------------------------------------------------------------
__global__ void k_cvt(const float* __restrict__ C32, unsigned short* __restrict__ CF) {
  int t = blockIdx.x * 512 + threadIdx.x;       // 0..262143
  int m = t >> 6;
  int n4 = (t & 63) * 4;
  f32x4 v = *(const f32x4*)(C32 + (long)m * DD + n4);
#pragma unroll
  for (int j = 0; j < 4; ++j) {
    int n = n4 + j;
    long fidx = ((long)((n >> 4) * 128 + (m >> 5))) * 512 +
                (((m >> 3) & 3) * 16 + (n & 15)) * 8 + (m & 7);
    CF[fidx] = f2bf(v[j]);
  }
}

// ---------------------------------------------------------------------------
// K8: fused final: out = aH*C + aL*(Hl + bconv)
// ---------------------------------------------------------------------------
__global__ void k_fin(const float* __restrict__ C32, const float* __restrict__ Hl,
                      const float* __restrict__ bconv, const float* __restrict__ aLp,
                      const float* __restrict__ aHp, float* __restrict__ outF) {
  int t = blockIdx.x * 512 + threadIdx.x;       // 0..262143
  int m = t >> 6;
  int n4 = (t & 63) * 4;
  const float aLv = aLp[0], aHv = aHp[0];
  f32x4 c = *(const f32x4*)(C32 + (long)m * DD + n4);
  f32x4 hv = *(const f32x4*)(Hl + (long)m * DD + n4);
  f32x4 bc = *(const f32x4*)(bconv + n4);
  f32x4 res;
  res[0] = aHv * c[0] + aLv * (hv[0] + bc[0]);
  res[1] = aHv * c[1] + aLv * (hv[1] + bc[1]);
  res[2] = aHv * c[2] + aLv * (hv[2] + bc[2]);
  res[3] = aHv * c[3] + aLv * (hv[3] + bc[3]);
  *(f32x4*)(outF + (long)m * DD + n4) = res;
}

// ---------------------------------------------------------------------------
// launcher
// ---------------------------------------------------------------------------
extern "C" void kernel_launch(void* const* d_in, const int* in_sizes, int n_in,
                              void* d_out, int out_size, void* d_ws, size_t ws_size,
                              hipStream_t stream) {
  const float* x     = (const float*)d_in[0];
  const int*   ei    = (const int*)d_in[1];
  const float* lap   = (const float*)d_in[2];
  const float* dinv  = (const float*)d_in[3];
  const float* Wh    = (const float*)d_in[4];
  const float* Wc    = (const float*)d_in[5];
  const float* bconv = (const float*)d_in[6];
  const float* aL    = (const float*)d_in[7];
  const float* aH    = (const float*)d_in[8];
  float* out = (float*)d_out;
  char* ws = (char*)d_ws;

  int* deg        = (int*)(ws);                          // 16 KB
  int* cursor     = (int*)(ws + (16 << 10));             // 16 KB
  int* row_start  = (int*)(ws + (32 << 10));             // 16.4 KB
  int* csr        = (int*)(ws + (64 << 10));             // 512 KB
  float* dis      = (float*)(ws + (576 << 10));          // 16 KB
  unsigned short* WFh = (unsigned short*)(ws + (1l << 20));               // 128 KB
  unsigned short* WFc = (unsigned short*)(ws + (1l << 20) + (128 << 10)); // 128 KB
  unsigned short* RF  = (unsigned short*)(ws + (2l << 20));  // 2 MB fragment layout
  unsigned short* T1F = (unsigned short*)(ws + (4l << 20));  // 2 MB
  unsigned short* T2F = (unsigned short*)(ws + (6l << 20));  // 2 MB
  float* XWs = (float*)(ws + (8l << 20));                    // 4 MB (dead after k_agg)
  float* C32 = (float*)(ws + (8l << 20));                    // 4 MB (reuses XWs)
  float* Hl  = (float*)(ws + (12l << 20));                   // 4 MB

  hipMemsetAsync(ws, 0, 32 << 10, stream);   // deg + cursor

  k_prep<<<1024, 256, 0, stream>>>(ei, deg, Wh, Wc, WFh, WFc);
  k_scan<<<1, 1024, 0, stream>>>(deg, row_start, dis);
  k_scatter<<<512, 256, 0, stream>>>(ei, row_start, cursor, csr);
  k_xw<<<256, 512, 0, stream>>>(x, WFh, WFc, RF, XWs, dis);
  k_agg<<<4096, 256, 0, stream>>>(XWs, row_start, csr, dis, Hl);

  // mm chain: T1 = dinv @ relu(xWh); T2 = lap @ T1; out = aH*(dinv @ T2) + ...
  hipMemsetAsync(C32, 0, 4 << 20, stream);
  k_mm3<<<512, 256, 0, stream>>>(dinv, RF, C32);
  k_cvt<<<512, 512, 0, stream>>>(C32, T1F);
  hipMemsetAsync(C32, 0, 4 << 20, stream);
  k_mm3<<<512, 256, 0, stream>>>(lap, T1F, C32);
  k_cvt<<<512, 512, 0, stream>>>(C32, T2F);
  hipMemsetAsync(C32, 0, 4 << 20, stream);
  k_mm3<<<512, 256, 0, stream>>>(dinv, T2F, C32);
  k_fin<<<512, 512, 0, stream>>>(C32, Hl, bconv, aL, aH, out);
}